// Round 4
// baseline (795.164 us; speedup 1.0000x reference)
//
#include <hip/hip_runtime.h>
#include <math.h>

#define NCLS 19      // known classes (void = 19 dropped)
#define NF   256     // feature length
#define HW   16384   // 128*128
#define ROWW 128     // w extent
#define PAD  257     // LDS stride pad (257%32==1 -> distinct labels hit distinct banks)
#define C2   (HW/2)  // channel stride in float2

__global__ __launch_bounds__(256) void zero_protos(float* __restrict__ g) {
    int i = blockIdx.x * 256 + threadIdx.x;
    if (i < NCLS * NF) g[i] = 0.f;
}

// grid 512, block 256. Each block: 4 rows (b,h); each thread: 2 adjacent pixels (float2).
// Key: loads hand-batched 16/8-deep into register arrays for memory-level parallelism —
// round-2 profile showed VGPR=16 (compiler serialized the loop: 640 GB/s, latency-bound).
__global__ __launch_bounds__(256) void accum_protos(const float* __restrict__ feat,
                                                    const int* __restrict__ labels,
                                                    float* __restrict__ gproto) {
    __shared__ float lds[NCLS * PAD];   // 19*257 = 4883 floats = 19.5 KB
    for (int i = threadIdx.x; i < NCLS * PAD; i += 256) lds[i] = 0.f;
    __syncthreads();

    const int tid = threadIdx.x;
    const int r   = tid >> 6;            // 0..3 : row within block
    const int w0  = (tid & 63) * 2;      // pixel pair
    const int row = blockIdx.x * 4 + r;  // 0..2047 == b*128 + h
    const int b   = row >> 7;
    const int h   = row & 127;

    const int2 lab = *(const int2*)(labels + row * ROWW + w0);
    const bool a0 = (lab.x < NCLS);
    const bool a1 = (lab.y < NCLS);

    if (a0 | a1) {
        const float2* p = (const float2*)(feat + ((size_t)b * NF * HW + (size_t)h * ROWW + w0));

        // ---- pass 1: sum of squares, 16 loads in flight ----
        float s0 = 0.f, s1 = 0.f;
        for (int f = 0; f < NF; f += 16) {
            float2 v[16];
            #pragma unroll
            for (int u = 0; u < 16; ++u) v[u] = p[(f + u) * C2];
            #pragma unroll
            for (int u = 0; u < 16; ++u) {
                s0 += v[u].x * v[u].x;
                s1 += v[u].y * v[u].y;
            }
        }
        const float r0 = a0 ? (1.f / fmaxf(sqrtf(s0), 1e-12f)) : 0.f;
        const float r1 = a1 ? (1.f / fmaxf(sqrtf(s1), 1e-12f)) : 0.f;
        const int  o0 = lab.x * PAD;
        const int  o1 = lab.y * PAD;

        // ---- pass 2: scaled scatter into LDS prototypes, 8 loads in flight ----
        // re-read is block-footprint 512 KB -> L2/L3-served (round-2 FETCH confirms)
        for (int f = 0; f < NF; f += 8) {
            float2 v[8];
            #pragma unroll
            for (int u = 0; u < 8; ++u) v[u] = p[(f + u) * C2];
            #pragma unroll
            for (int u = 0; u < 8; ++u) {
                if (a0) atomicAdd(&lds[o0 + f + u], v[u].x * r0);
                if (a1) atomicAdd(&lds[o1 + f + u], v[u].y * r1);
            }
        }
    }
    __syncthreads();

    // flush block-local prototypes to global accumulator
    for (int i = threadIdx.x; i < NCLS * NF; i += 256) {
        const int c = i >> 8;        // i / 256
        const int f = i & 255;       // i % 255
        const float v = lds[c * PAD + (i & 255)];
        if (v != 0.f) atomicAdd(&gproto[(c << 8) | (i & 255)], v);
    }
}

// grid 19, block 256. Block c: normalize prototype column c, write transposed out[f*19+c].
__global__ __launch_bounds__(256) void normalize_protos(const float* __restrict__ gproto,
                                                        float* __restrict__ out) {
    __shared__ float ws[4];
    const int c = blockIdx.x;
    const int f = threadIdx.x;
    const float v = gproto[c * NF + f];

    float s = v * v;
    #pragma unroll
    for (int off = 32; off > 0; off >>= 1) s += __shfl_down(s, off, 64);
    if ((f & 63) == 0) ws[f >> 6] = s;
    __syncthreads();
    const float tot = ws[0] + ws[1] + ws[2] + ws[3];
    const float rn = 1.f / fmaxf(sqrtf(tot), 1e-12f);
    out[f * NCLS + c] = v * rn;
}

extern "C" void kernel_launch(void* const* d_in, const int* in_sizes, int n_in,
                              void* d_out, int out_size, void* d_ws, size_t ws_size,
                              hipStream_t stream) {
    const float* feat   = (const float*)d_in[0];
    const int*   labels = (const int*)d_in[1];
    float* out    = (float*)d_out;
    float* gproto = (float*)d_ws;    // NCLS*NF = 4864 floats

    zero_protos<<<NCLS, 256, 0, stream>>>(gproto);              // 19*256 == 4864
    accum_protos<<<512, 256, 0, stream>>>(feat, labels, gproto);
    normalize_protos<<<NCLS, 256, 0, stream>>>(gproto, out);
}

// Round 5
// 772.800 us; speedup vs baseline: 1.0289x; 1.0289x over previous
//
#include <hip/hip_runtime.h>
#include <math.h>

#define NCLS 19      // known classes (void = 19 dropped)
#define NF   256     // feature length
#define HW   16384   // 128*128 pixels per image
#define NB   16      // batch
#define PX   (NB*HW) // 262144 total pixels

// ---- K0: zero scratch (nrm2 accumulator + gproto) ----
__global__ __launch_bounds__(256) void zero_ws(float* __restrict__ nrm2,
                                               float* __restrict__ gproto) {
    int i = blockIdx.x * 256 + threadIdx.x;
    if (i < PX) nrm2[i] = 0.f;
    if (i < NCLS * NF) gproto[i] = 0.f;
}

// ---- K1: per-pixel sum-of-squares, contiguous streaming ----
// grid 512: b = g>>5, f0 = (g&31)*8. Block sweeps 8 whole f-slices of image b.
// Per k-step: 8 loads (one per slice) of dwordx4, 1KB contiguous per wave-inst.
// Per-pixel partials flushed with fire-and-forget atomicAdd (nrm2 = 1MB, L2-resident).
__global__ __launch_bounds__(256) void sumsq_kernel(const float* __restrict__ feat,
                                                    float* __restrict__ nrm2) {
    const int g  = blockIdx.x;
    const int b  = g >> 5;
    const int f0 = (g & 31) << 3;
    const int t  = threadIdx.x;

    const float* base = feat + (size_t)(b * NF + f0) * HW + t * 4;
    float* np = nrm2 + b * HW + t * 4;

    for (int k = 0; k < 16; ++k) {           // pixel chunk: p = k*1024 + t*4 + j
        float4 v[8];
        #pragma unroll
        for (int s = 0; s < 8; ++s)
            v[s] = *(const float4*)(base + (size_t)s * HW + k * 1024);
        float a0 = 0.f, a1 = 0.f, a2 = 0.f, a3 = 0.f;
        #pragma unroll
        for (int s = 0; s < 8; ++s) {
            a0 += v[s].x * v[s].x;
            a1 += v[s].y * v[s].y;
            a2 += v[s].z * v[s].z;
            a3 += v[s].w * v[s].w;
        }
        atomicAdd(&np[k * 1024 + 0], a0);
        atomicAdd(&np[k * 1024 + 1], a1);
        atomicAdd(&np[k * 1024 + 2], a2);
        atomicAdd(&np[k * 1024 + 3], a3);
    }
}

// ---- K2: nrm2 -> 1/max(sqrt(nrm2), eps), in place ----
__global__ __launch_bounds__(256) void rinv_kernel(float* __restrict__ nrm2) {
    int i = (blockIdx.x * 256 + threadIdx.x) * 4;
    float4 s = *(float4*)(nrm2 + i);
    float4 r;
    r.x = 1.f / fmaxf(sqrtf(s.x), 1e-12f);
    r.y = 1.f / fmaxf(sqrtf(s.y), 1e-12f);
    r.z = 1.f / fmaxf(sqrtf(s.z), 1e-12f);
    r.w = 1.f / fmaxf(sqrtf(s.w), 1e-12f);
    *(float4*)(nrm2 + i) = r;
}

// ---- K3: scaled scatter into class prototypes, contiguous streaming ----
// grid 512: same (b, f0) tiling as K1. LDS proto tile 19 x 9 (9 coprime 32:
// 19 distinct labels -> 19 distinct banks). Flush = 152 global atomics/block.
__global__ __launch_bounds__(256) void scatter_kernel(const float* __restrict__ feat,
                                                      const int* __restrict__ labels,
                                                      const float* __restrict__ rinv,
                                                      float* __restrict__ gproto) {
    __shared__ float lp[NCLS * 9];
    const int t = threadIdx.x;
    for (int i = t; i < NCLS * 9; i += 256) lp[i] = 0.f;
    __syncthreads();

    const int g  = blockIdx.x;
    const int b  = g >> 5;
    const int f0 = (g & 31) << 3;

    const float* base = feat + (size_t)(b * NF + f0) * HW + t * 4;
    const int*   lb   = labels + b * HW + t * 4;
    const float* rv   = rinv   + b * HW + t * 4;

    for (int k = 0; k < 16; ++k) {
        const int4   l4 = *(const int4*)(lb + k * 1024);
        const float4 r4 = *(const float4*)(rv + k * 1024);
        float4 v[8];
        #pragma unroll
        for (int s = 0; s < 8; ++s)
            v[s] = *(const float4*)(base + (size_t)s * HW + k * 1024);
        #pragma unroll
        for (int s = 0; s < 8; ++s) {
            if (l4.x < NCLS) atomicAdd(&lp[l4.x * 9 + s], v[s].x * r4.x);
            if (l4.y < NCLS) atomicAdd(&lp[l4.y * 9 + s], v[s].y * r4.y);
            if (l4.z < NCLS) atomicAdd(&lp[l4.z * 9 + s], v[s].z * r4.z);
            if (l4.w < NCLS) atomicAdd(&lp[l4.w * 9 + s], v[s].w * r4.w);
        }
    }
    __syncthreads();

    for (int i = t; i < NCLS * 8; i += 256) {
        const int c = i >> 3, fr = i & 7;
        const float val = lp[c * 9 + fr];
        if (val != 0.f) atomicAdd(&gproto[c * NF + f0 + fr], val);
    }
}

// ---- K4: normalize prototype columns, write transposed out[f*19+c] ----
__global__ __launch_bounds__(256) void normalize_protos(const float* __restrict__ gproto,
                                                        float* __restrict__ out) {
    __shared__ float ws[4];
    const int c = blockIdx.x;
    const int f = threadIdx.x;
    const float v = gproto[c * NF + f];

    float s = v * v;
    #pragma unroll
    for (int off = 32; off > 0; off >>= 1) s += __shfl_down(s, off, 64);
    if ((f & 63) == 0) ws[f >> 6] = s;
    __syncthreads();
    const float tot = ws[0] + ws[1] + ws[2] + ws[3];
    const float rn = 1.f / fmaxf(sqrtf(tot), 1e-12f);
    out[f * NCLS + c] = v * rn;
}

extern "C" void kernel_launch(void* const* d_in, const int* in_sizes, int n_in,
                              void* d_out, int out_size, void* d_ws, size_t ws_size,
                              hipStream_t stream) {
    const float* feat   = (const float*)d_in[0];
    const int*   labels = (const int*)d_in[1];
    float* out    = (float*)d_out;
    float* gproto = (float*)d_ws;              // 4864 floats (slot of 8192)
    float* nrm2   = (float*)d_ws + 8192;       // 262144 floats (1 MB)

    zero_ws<<<PX / 256, 256, 0, stream>>>(nrm2, gproto);      // 1024 blocks
    sumsq_kernel<<<512, 256, 0, stream>>>(feat, nrm2);
    rinv_kernel<<<PX / 1024, 256, 0, stream>>>(nrm2);         // 256 blocks
    scatter_kernel<<<512, 256, 0, stream>>>(feat, labels, nrm2, gproto);
    normalize_protos<<<NCLS, 256, 0, stream>>>(gproto, out);
}